// Round 10
// baseline (628.609 us; speedup 1.0000x reference)
//
#include <hip/hip_runtime.h>
#include <math.h>

#define NROWS 8192
#define DIM   1024
#define DIM2  2048           // merged hi|lo K dimension
#define KSEL  5
#define TOPK  6
#define QB    128            // queries per block
#define KBB   128            // keys per block
#define NKB   (NROWS / KBB)  // key tiles = 64

typedef __attribute__((ext_vector_type(8))) short bf16x8;
typedef __attribute__((ext_vector_type(4))) float f32x4;

// ---------------------------------------------------------------------------
// ws layout:
//   [0]          : int match counter
//   [256]        : Q2 bf16[8192][2048]  (hi | lo, XOR-swizzled)   32 MB
//   [+32M]       : K2 bf16[8192][2048]  (hi | lo, XOR-swizzled)   32 MB
//   [+64M]       : partials_t float2[64*6][8192]  (TRANSPOSED, 25 MB)
//
// Round-10: round-9 single-accumulator-lifetime structure with the 4x4 acc
// (64 AGPR): lists live only in the epilogue -> ~150-165 unified regs ->
// __launch_bounds__(256,3) gives 12 waves/CU = the occupancy where m97's
// 874-912 TF plateau lives (m114 implicit overlap). Partials are stored
// TRANSPOSED [list][row] so the merge kernel's loads are lane-coalesced
// (round-9's 138 us non-gemm leak was the uncoalesced per-row scan).
// XOR global swizzle keeps LDS fragment reads conflict-free (r7: 3.4e7->0).
// ---------------------------------------------------------------------------

__device__ __forceinline__ unsigned short f2bf(float x) {
    unsigned u = __float_as_uint(x);
    unsigned r = (u + 0x7fffu + ((u >> 16) & 1u)) >> 16;   // RNE
    return (unsigned short)r;
}
__device__ __forceinline__ float bf2f(unsigned short h) {
    return __uint_as_float(((unsigned)h) << 16);
}

// full tie-break compare (merge paths — arbitrary id order there)
__device__ __forceinline__ bool better(float v, int id, float v2, int id2) {
    return (v > v2) || (v == v2 && id < id2);
}
__device__ __forceinline__ void insert6(float v, int id, float* tv, int* ti) {
    if (!better(v, id, tv[TOPK - 1], ti[TOPK - 1])) return;
    int j = TOPK - 1;
    while (j > 0 && better(v, id, tv[j - 1], ti[j - 1])) {
        tv[j] = tv[j - 1]; ti[j] = ti[j - 1]; --j;
    }
    tv[j] = v; ti[j] = id;
}

// branchless strict insert (ascending-id stream => strict '>' is exact).
__device__ __forceinline__ void ins6(float v, int id, float* tv, int* ti) {
    if (v <= tv[5]) return;
    bool gt[6];
#pragma unroll
    for (int j = 0; j < 6; ++j) gt[j] = v > tv[j];
#pragma unroll
    for (int j = 5; j >= 1; --j)
        if (gt[j - 1]) { tv[j] = tv[j - 1]; ti[j] = ti[j - 1]; }
    if (gt[0]) { tv[0] = v; ti[0] = id; }
#pragma unroll
    for (int j = 1; j < 6; ++j)
        if (gt[j] && !gt[j - 1]) { tv[j] = v; ti[j] = id; }
}

__device__ __forceinline__ void async16(const unsigned short* g, unsigned short* l) {
    __builtin_amdgcn_global_load_lds(
        (const __attribute__((address_space(1))) void*)g,
        (__attribute__((address_space(3))) void*)l, 16, 0, 0);
}

// --- 1) normalize + split hi/lo bf16, packed [hi|lo], XOR-swizzled chunks ---
__global__ __launch_bounds__(128) void prep_kernel(
        const float* __restrict__ q, const float* __restrict__ kb,
        unsigned short* __restrict__ Q2, unsigned short* __restrict__ K2) {
    const int b = blockIdx.x;
    const bool isQ = (b < NROWS);
    const int r = isQ ? b : b - NROWS;
    const float* src = (isQ ? q : kb) + (size_t)r * DIM;
    unsigned short* D = (isQ ? Q2 : K2) + (size_t)r * DIM2;

    const int t = threadIdx.x;          // 0..127, handles elems 8t..8t+7
    float4 v0 = *(const float4*)(src + t * 8);
    float4 v1 = *(const float4*)(src + t * 8 + 4);
    float s = v0.x * v0.x + v0.y * v0.y + v0.z * v0.z + v0.w * v0.w
            + v1.x * v1.x + v1.y * v1.y + v1.z * v1.z + v1.w * v1.w;
    for (int o = 32; o; o >>= 1) s += __shfl_down(s, o, 64);
    __shared__ float wsum[2];
    __shared__ float inv_s;
    int lane = t & 63, wid = t >> 6;
    if (lane == 0) wsum[wid] = s;
    __syncthreads();
    if (t == 0)
        inv_s = 1.0f / fmaxf(sqrtf(wsum[0] + wsum[1]), 1e-12f);
    __syncthreads();
    const float inv = inv_s;

    float xs[8] = {v0.x * inv, v0.y * inv, v0.z * inv, v0.w * inv,
                   v1.x * inv, v1.y * inv, v1.z * inv, v1.w * inv};
    bf16x8 hi, lo;
#pragma unroll
    for (int i = 0; i < 8; ++i) {
        unsigned short h = f2bf(xs[i]);
        hi[i] = (short)h;
        lo[i] = (short)f2bf(xs[i] - bf2f(h));
    }
    // chunk t: k-block t>>3, chunk-in-block t&7, swizzled by row&7
    const int off = (t >> 3) * 64 + (((t & 7) ^ (r & 7)) * 8);
    *(bf16x8*)(D + off)       = hi;
    *(bf16x8*)(D + DIM + off) = lo;
}

// --- 2) 128x128 transposed MFMA GEMM + epilogue top-6 -----------------------
__global__ __launch_bounds__(256, 3) void gemm_topk_kernel(
        const unsigned short* __restrict__ Q2, const unsigned short* __restrict__ K2,
        float2* __restrict__ partials_t) {
    // K-loop: Ks[128*64] (16 KB) + Qs[128*64] (16 KB); merge 48 KB (alias)
    __shared__ __align__(16) char smem[49152];
    unsigned short* Ks = (unsigned short*)smem;          // A-operand (keys)
    unsigned short* Qs = Ks + KBB * 64;                  // B-operand (queries)
    float2* mbuf = (float2*)smem;                        // [128 q][8 slot][6]

    const int tid = threadIdx.x;
    const int w = tid >> 6, l = tid & 63;
    const int l15 = l & 15, l4 = l >> 4;
    const int qbase = blockIdx.x * QB;
    const int kbase = blockIdx.y * KBB;
    const int wkh = w & 1;               // key half   (64 keys)
    const int wqh = w >> 1;              // query half (64 queries)

    const int arow  = tid >> 3;          // 0..31 (+ j*32)
    const int akoff = (tid & 7) * 8;     // swizzled position within k-block

    const int xr = l15 & 7;
    const int fa_row = (wkh * 64 + l15) * 64;    // + mt*1024
    const int fb_row = (wqh * 64 + l15) * 64;    // + nt*1024

    const size_t qstage = (size_t)(qbase + arow) * DIM2 + akoff;
    const size_t kstage = (size_t)(kbase + arow) * DIM2 + akoff;

    f32x4 acc[4][4];   // [mt = key-tile][nt = query-tile]
#pragma unroll
    for (int mt = 0; mt < 4; ++mt)
#pragma unroll
        for (int nt = 0; nt < 4; ++nt) acc[mt][nt] = (f32x4){0.f, 0.f, 0.f, 0.f};

#pragma unroll 1
    for (int k0 = 0; k0 < DIM2; k0 += 64) {
#pragma unroll
        for (int j = 0; j < 4; ++j)
            async16(K2 + kstage + (size_t)j * 32 * DIM2 + k0,
                    Ks + (tid + j * 256) * 8);
#pragma unroll
        for (int j = 0; j < 4; ++j)
            async16(Q2 + qstage + (size_t)j * 32 * DIM2 + k0,
                    Qs + (tid + j * 256) * 8);
        __syncthreads();   // drains vmcnt (global_load_lds)
#pragma unroll
        for (int ks = 0; ks < 2; ++ks) {
            const int p8 = ((ks * 4 + l4) ^ xr) * 8;
            bf16x8 af[4], bf[4];
#pragma unroll
            for (int mt = 0; mt < 4; ++mt)
                af[mt] = *(const bf16x8*)(Ks + fa_row + mt * 1024 + p8);
#pragma unroll
            for (int nt = 0; nt < 4; ++nt)
                bf[nt] = *(const bf16x8*)(Qs + fb_row + nt * 1024 + p8);
#pragma unroll
            for (int mt = 0; mt < 4; ++mt)
#pragma unroll
                for (int nt = 0; nt < 4; ++nt)
                    acc[mt][nt] = __builtin_amdgcn_mfma_f32_16x16x32_bf16(
                        af[mt], bf[nt], acc[mt][nt], 0, 0, 0);
        }
        __syncthreads();
    }

    // ---- epilogue top-6 (once per block): 16 keys/thread per nt-list ------
    float tvl[4][6]; int til[4][6];
#pragma unroll
    for (int n = 0; n < 4; ++n)
#pragma unroll
        for (int i = 0; i < 6; ++i) { tvl[n][i] = -INFINITY; til[n][i] = 0x7fffffff; }

#pragma unroll
    for (int nt = 0; nt < 4; ++nt) {
#pragma unroll
        for (int mt = 0; mt < 4; ++mt) {
            const f32x4 a = acc[mt][nt];
            const float m4 = fmaxf(fmaxf(a.x, a.y), fmaxf(a.z, a.w));
            if (m4 > tvl[nt][5]) {
                const int kk = kbase + wkh * 64 + mt * 16 + l4 * 4;
                ins6(a.x, kk + 0, tvl[nt], til[nt]);
                ins6(a.y, kk + 1, tvl[nt], til[nt]);
                ins6(a.z, kk + 2, tvl[nt], til[nt]);
                ins6(a.w, kk + 3, tvl[nt], til[nt]);
            }
        }
    }

    // ---- block merge: 8 slots per query -> 1 list per query ---------------
    __syncthreads();                     // all K-loop LDS reads done
    const int slot = wkh * 4 + l4;       // 0..7
#pragma unroll
    for (int nt = 0; nt < 4; ++nt) {
        const int ql = wqh * 64 + nt * 16 + l15;     // local query 0..127
        float2* dst = mbuf + ((size_t)ql * 8 + slot) * 6;
#pragma unroll
        for (int e = 0; e < 6; ++e)
            dst[e] = make_float2(tvl[nt][e], __int_as_float(til[nt][e]));
    }
    __syncthreads();

    if (tid < 128) {                     // one thread per query merges 8 lists
        float tv[6]; int ti[6];
#pragma unroll
        for (int i = 0; i < 6; ++i) { tv[i] = -INFINITY; ti[i] = 0x7fffffff; }
        const float2* src = mbuf + (size_t)tid * 48;
        for (int e = 0; e < 48; ++e) {
            float2 p = src[e];
            if (p.x < tv[5]) continue;
            insert6(p.x, __float_as_int(p.y), tv, ti);
        }
        // transposed store: coalesced across tid for each rank e
        const int row = qbase + tid;
#pragma unroll
        for (int i = 0; i < 6; ++i)
            partials_t[(size_t)(blockIdx.y * 6 + i) * NROWS + row] =
                make_float2(tv[i], __int_as_float(ti[i]));
    }
}

// --- 3) merge 64 transposed lists per row, count matches on ranks 1..5 ------
__global__ __launch_bounds__(256) void merge_kernel(
        const float2* __restrict__ partials_t,
        const int* __restrict__ query_ids, const int* __restrict__ key_ids,
        int* __restrict__ counter) {
    int row = blockIdx.x * blockDim.x + threadIdx.x;
    float tv[TOPK]; int ti[TOPK];
#pragma unroll
    for (int i = 0; i < TOPK; ++i) { tv[i] = -INFINITY; ti[i] = 0x7fffffff; }
#pragma unroll 8
    for (int l = 0; l < NKB * TOPK; ++l) {
        float2 e = partials_t[(size_t)l * NROWS + row];   // lane-coalesced
        if (e.x < tv[TOPK - 1]) continue;
        insert6(e.x, __float_as_int(e.y), tv, ti);
    }
    int qid = query_ids[row];
    int cnt = 0;
#pragma unroll
    for (int r = 1; r < TOPK; ++r)
        cnt += (key_ids[ti[r]] == qid) ? 1 : 0;

    for (int o = 32; o; o >>= 1) cnt += __shfl_down(cnt, o, 64);
    __shared__ int sc[4];
    int lane = threadIdx.x & 63, wid = threadIdx.x >> 6;
    if (lane == 0) sc[wid] = cnt;
    __syncthreads();
    if (threadIdx.x == 0) atomicAdd(counter, sc[0] + sc[1] + sc[2] + sc[3]);
}

// --- 4) finalize ------------------------------------------------------------
__global__ void finalize_kernel(const int* __restrict__ counter,
                                float* __restrict__ out) {
    out[0] = (float)(*counter) / (float)(NROWS * KSEL);
}

extern "C" void kernel_launch(void* const* d_in, const int* in_sizes, int n_in,
                              void* d_out, int out_size, void* d_ws, size_t ws_size,
                              hipStream_t stream) {
    (void)in_sizes; (void)n_in; (void)out_size; (void)ws_size;
    const int*   query_ids = (const int*)d_in[0];
    const int*   key_ids   = (const int*)d_in[1];
    const float* q         = (const float*)d_in[2];
    const float* kb        = (const float*)d_in[3];

    char* ws = (char*)d_ws;
    const size_t MB32 = (size_t)NROWS * DIM2 * sizeof(unsigned short);  // 32 MB
    int*            counter  = (int*)ws;
    unsigned short* Q2       = (unsigned short*)(ws + 256);
    unsigned short* K2       = (unsigned short*)(ws + 256 + MB32);
    float2*         partials = (float2*)(ws + 256 + 2 * MB32);

    hipMemsetAsync(counter, 0, sizeof(int), stream);
    prep_kernel<<<2 * NROWS, 128, 0, stream>>>(q, kb, Q2, K2);
    gemm_topk_kernel<<<dim3(NROWS / QB, NKB), 256, 0, stream>>>(Q2, K2, partials);
    merge_kernel<<<NROWS / 256, 256, 0, stream>>>(partials, query_ids, key_ids, counter);
    finalize_kernel<<<1, 1, 0, stream>>>(counter, (float*)d_out);
}

// Round 11
// 459.698 us; speedup vs baseline: 1.3674x; 1.3674x over previous
//
#include <hip/hip_runtime.h>
#include <math.h>

#define NROWS 8192
#define DIM   1024
#define DIM2  2048           // merged hi|lo K dimension
#define KSEL  5
#define TOPK  6
#define QB    128            // queries per block
#define KBB   256            // keys per block
#define NKB   (NROWS / KBB)  // key blocks = 32 (also lists per row)
#define PS    51             // mbuf per-query stride in float2 (pad 48->51)

typedef __attribute__((ext_vector_type(8))) short bf16x8;
typedef __attribute__((ext_vector_type(4))) float f32x4;

// ---------------------------------------------------------------------------
// ws layout:
//   [0]          : int match counter
//   [256]        : Q2 bf16[8192][2048]  (hi | lo, XOR-swizzled)   32 MB
//   [+32M]       : K2 bf16[8192][2048]  (hi | lo, XOR-swizzled)   32 MB
//   [+64M]       : partials float2[8192][32][6]  (12.6 MB)
//
// Round-11 = measured-best recomposition:
//  * gemm: round-9 256x128 tile verbatim (364 us, 756 TF) — r10 proved the
//    128x128 "occupancy" variant is net worse (reads/MFMA 0.5 vs 0.375,
//    2x barriers, occupancy gain never materialized).
//  * mbuf padded 48->51 float2/query: r10's 4.3e7 bank conflicts were the
//    64-way epilogue merge reads (384 B ≡ bank-0 lane stride).
//  * merge kernel parallelized 8 threads/row: r9/r10 evidence shows it is
//    latency-bound (serial 192/384-deep dependent chains, 32 blocks).
// ---------------------------------------------------------------------------

__device__ __forceinline__ unsigned short f2bf(float x) {
    unsigned u = __float_as_uint(x);
    unsigned r = (u + 0x7fffu + ((u >> 16) & 1u)) >> 16;   // RNE
    return (unsigned short)r;
}
__device__ __forceinline__ float bf2f(unsigned short h) {
    return __uint_as_float(((unsigned)h) << 16);
}

// full tie-break compare (merge paths — arbitrary id order there)
__device__ __forceinline__ bool better(float v, int id, float v2, int id2) {
    return (v > v2) || (v == v2 && id < id2);
}
__device__ __forceinline__ void insert6(float v, int id, float* tv, int* ti) {
    if (!better(v, id, tv[TOPK - 1], ti[TOPK - 1])) return;
    int j = TOPK - 1;
    while (j > 0 && better(v, id, tv[j - 1], ti[j - 1])) {
        tv[j] = tv[j - 1]; ti[j] = ti[j - 1]; --j;
    }
    tv[j] = v; ti[j] = id;
}

// branchless strict insert (ascending-id stream => strict '>' is exact).
__device__ __forceinline__ void ins6(float v, int id, float* tv, int* ti) {
    if (v <= tv[5]) return;
    bool gt[6];
#pragma unroll
    for (int j = 0; j < 6; ++j) gt[j] = v > tv[j];
#pragma unroll
    for (int j = 5; j >= 1; --j)
        if (gt[j - 1]) { tv[j] = tv[j - 1]; ti[j] = ti[j - 1]; }
    if (gt[0]) { tv[0] = v; ti[0] = id; }
#pragma unroll
    for (int j = 1; j < 6; ++j)
        if (gt[j] && !gt[j - 1]) { tv[j] = v; ti[j] = id; }
}

__device__ __forceinline__ void async16(const unsigned short* g, unsigned short* l) {
    __builtin_amdgcn_global_load_lds(
        (const __attribute__((address_space(1))) void*)g,
        (__attribute__((address_space(3))) void*)l, 16, 0, 0);
}

// --- 1) normalize + split hi/lo bf16, packed [hi|lo], XOR-swizzled chunks ---
__global__ __launch_bounds__(128) void prep_kernel(
        const float* __restrict__ q, const float* __restrict__ kb,
        unsigned short* __restrict__ Q2, unsigned short* __restrict__ K2) {
    const int b = blockIdx.x;
    const bool isQ = (b < NROWS);
    const int r = isQ ? b : b - NROWS;
    const float* src = (isQ ? q : kb) + (size_t)r * DIM;
    unsigned short* D = (isQ ? Q2 : K2) + (size_t)r * DIM2;

    const int t = threadIdx.x;          // 0..127, handles elems 8t..8t+7
    float4 v0 = *(const float4*)(src + t * 8);
    float4 v1 = *(const float4*)(src + t * 8 + 4);
    float s = v0.x * v0.x + v0.y * v0.y + v0.z * v0.z + v0.w * v0.w
            + v1.x * v1.x + v1.y * v1.y + v1.z * v1.z + v1.w * v1.w;
    for (int o = 32; o; o >>= 1) s += __shfl_down(s, o, 64);
    __shared__ float wsum[2];
    __shared__ float inv_s;
    int lane = t & 63, wid = t >> 6;
    if (lane == 0) wsum[wid] = s;
    __syncthreads();
    if (t == 0)
        inv_s = 1.0f / fmaxf(sqrtf(wsum[0] + wsum[1]), 1e-12f);
    __syncthreads();
    const float inv = inv_s;

    float xs[8] = {v0.x * inv, v0.y * inv, v0.z * inv, v0.w * inv,
                   v1.x * inv, v1.y * inv, v1.z * inv, v1.w * inv};
    bf16x8 hi, lo;
#pragma unroll
    for (int i = 0; i < 8; ++i) {
        unsigned short h = f2bf(xs[i]);
        hi[i] = (short)h;
        lo[i] = (short)f2bf(xs[i] - bf2f(h));
    }
    // chunk t: k-block t>>3, chunk-in-block t&7, swizzled by row&7
    const int off = (t >> 3) * 64 + (((t & 7) ^ (r & 7)) * 8);
    *(bf16x8*)(D + off)       = hi;
    *(bf16x8*)(D + DIM + off) = lo;
}

// --- 2) 256x128 transposed MFMA GEMM + in-register top-6 --------------------
__global__ __launch_bounds__(256, 2) void gemm_topk_kernel(
        const unsigned short* __restrict__ Q2, const unsigned short* __restrict__ K2,
        float2* __restrict__ partials) {
    // K-loop: Ks[256*64] (32 KB) + Qs[128*64] (16 KB); merge: 128*PS float2
    __shared__ __align__(16) char smem[53248];
    unsigned short* Ks = (unsigned short*)smem;          // A-operand (keys)
    unsigned short* Qs = Ks + KBB * 64;                  // B-operand (queries)
    float2* mbuf = (float2*)smem;                        // [128 q][PS]

    const int tid = threadIdx.x;
    const int w = tid >> 6, l = tid & 63;
    const int l15 = l & 15, l4 = l >> 4;
    const int qbase = blockIdx.x * QB;
    const int kbase = blockIdx.y * KBB;
    const int wkh = w & 1;               // key half   (128 keys)
    const int wqh = w >> 1;              // query half (64 queries)

    const int arow  = tid >> 3;          // 0..31 (+ j*32)
    const int akoff = (tid & 7) * 8;     // swizzled position within k-block

    const int xr = l15 & 7;
    const int fa_row = (wkh * 128 + l15) * 64;   // + mt*1024
    const int fb_row = (wqh * 64 + l15) * 64;    // + nt*1024

    const size_t qstage = (size_t)(qbase + arow) * DIM2 + akoff;
    const size_t kstage = (size_t)(kbase + arow) * DIM2 + akoff;

    f32x4 acc[8][4];   // [mt = key-tile][nt = query-tile]
#pragma unroll
    for (int mt = 0; mt < 8; ++mt)
#pragma unroll
        for (int nt = 0; nt < 4; ++nt) acc[mt][nt] = (f32x4){0.f, 0.f, 0.f, 0.f};

#pragma unroll 1
    for (int k0 = 0; k0 < DIM2; k0 += 64) {
#pragma unroll
        for (int j = 0; j < 8; ++j)
            async16(K2 + kstage + (size_t)j * 32 * DIM2 + k0,
                    Ks + (tid + j * 256) * 8);
#pragma unroll
        for (int j = 0; j < 4; ++j)
            async16(Q2 + qstage + (size_t)j * 32 * DIM2 + k0,
                    Qs + (tid + j * 256) * 8);
        __syncthreads();   // drains vmcnt (global_load_lds)
#pragma unroll
        for (int ks = 0; ks < 2; ++ks) {
            const int p8 = ((ks * 4 + l4) ^ xr) * 8;
            bf16x8 af[8], bf[4];
#pragma unroll
            for (int mt = 0; mt < 8; ++mt)
                af[mt] = *(const bf16x8*)(Ks + fa_row + mt * 1024 + p8);
#pragma unroll
            for (int nt = 0; nt < 4; ++nt)
                bf[nt] = *(const bf16x8*)(Qs + fb_row + nt * 1024 + p8);
#pragma unroll
            for (int mt = 0; mt < 8; ++mt)
#pragma unroll
                for (int nt = 0; nt < 4; ++nt)
                    acc[mt][nt] = __builtin_amdgcn_mfma_f32_16x16x32_bf16(
                        af[mt], bf[nt], acc[mt][nt], 0, 0, 0);
        }
        __syncthreads();
    }

    // ---- in-register top-6 (once per block): 32 keys/thread per nt-list ----
    float tvl[4][6]; int til[4][6];
#pragma unroll
    for (int n = 0; n < 4; ++n)
#pragma unroll
        for (int i = 0; i < 6; ++i) { tvl[n][i] = -INFINITY; til[n][i] = 0x7fffffff; }

#pragma unroll
    for (int nt = 0; nt < 4; ++nt) {
#pragma unroll
        for (int mt = 0; mt < 8; ++mt) {
            const f32x4 a = acc[mt][nt];
            const float m4 = fmaxf(fmaxf(a.x, a.y), fmaxf(a.z, a.w));
            if (m4 > tvl[nt][5]) {
                const int kk = kbase + wkh * 128 + mt * 16 + l4 * 4;
                ins6(a.x, kk + 0, tvl[nt], til[nt]);
                ins6(a.y, kk + 1, tvl[nt], til[nt]);
                ins6(a.z, kk + 2, tvl[nt], til[nt]);
                ins6(a.w, kk + 3, tvl[nt], til[nt]);
            }
        }
    }

    // ---- block merge: 8 slots per query -> 1 list per query ---------------
    __syncthreads();                     // all K-loop LDS reads done
    const int slot = wkh * 4 + l4;       // 0..7
#pragma unroll
    for (int nt = 0; nt < 4; ++nt) {
        const int ql = wqh * 64 + nt * 16 + l15;     // local query 0..127
        float2* dst = mbuf + (size_t)ql * PS + slot * 6;
#pragma unroll
        for (int e = 0; e < 6; ++e)
            dst[e] = make_float2(tvl[nt][e], __int_as_float(til[nt][e]));
    }
    __syncthreads();

    if (tid < 128) {                     // one thread per query merges 8 lists
        float tv[6]; int ti[6];
#pragma unroll
        for (int i = 0; i < 6; ++i) { tv[i] = -INFINITY; ti[i] = 0x7fffffff; }
        const float2* src = mbuf + (size_t)tid * PS;
        for (int e = 0; e < 48; ++e) {
            float2 p = src[e];
            if (p.x < tv[5]) continue;
            insert6(p.x, __float_as_int(p.y), tv, ti);
        }
        size_t off = ((size_t)(qbase + tid) * NKB + blockIdx.y) * TOPK;
#pragma unroll
        for (int i = 0; i < 6; ++i)
            partials[off + i] = make_float2(tv[i], __int_as_float(ti[i]));
    }
}

// --- 3) parallel merge: 8 threads/row over 32 lists, count ranks 1..5 -------
__global__ __launch_bounds__(256) void merge_kernel(
        const float2* __restrict__ partials,
        const int* __restrict__ query_ids, const int* __restrict__ key_ids,
        int* __restrict__ counter) {
    __shared__ float2 lbuf[32][49];      // [row-in-block][8 parts * 6, pad 49]
    __shared__ int sc[32];
    const int tid  = threadIdx.x;
    const int rloc = tid >> 3;           // 0..31
    const int part = tid & 7;            // 0..7
    const int row  = blockIdx.x * 32 + rloc;

    // stage 1: each thread merges 4 of the 32 lists (24 entries, coalesced)
    float tv[6]; int ti[6];
#pragma unroll
    for (int i = 0; i < 6; ++i) { tv[i] = -INFINITY; ti[i] = 0x7fffffff; }
    const float2* src = partials + ((size_t)row * NKB + part * 4) * TOPK;
#pragma unroll
    for (int e = 0; e < 24; ++e) {
        float2 p = src[e];
        if (p.x < tv[5]) continue;
        insert6(p.x, __float_as_int(p.y), tv, ti);
    }
#pragma unroll
    for (int i = 0; i < 6; ++i)
        lbuf[rloc][part * 6 + i] = make_float2(tv[i], __int_as_float(ti[i]));
    __syncthreads();

    // stage 2: one thread per row merges the 8 partial lists + counts
    if (part == 0) {
        float tv2[6]; int ti2[6];
#pragma unroll
        for (int i = 0; i < 6; ++i) { tv2[i] = -INFINITY; ti2[i] = 0x7fffffff; }
#pragma unroll
        for (int e = 0; e < 48; ++e) {
            float2 p = lbuf[rloc][e];
            if (p.x < tv2[5]) continue;
            insert6(p.x, __float_as_int(p.y), tv2, ti2);
        }
        const int qid = query_ids[row];
        int cnt = 0;
#pragma unroll
        for (int r = 1; r < TOPK; ++r)
            cnt += (key_ids[ti2[r]] == qid) ? 1 : 0;
        sc[rloc] = cnt;
    }
    __syncthreads();
    if (tid < 32) {
        int c = sc[tid];
        for (int o = 16; o; o >>= 1) c += __shfl_down(c, o, 64);
        if (tid == 0) atomicAdd(counter, c);
    }
}

// --- 4) finalize ------------------------------------------------------------
__global__ void finalize_kernel(const int* __restrict__ counter,
                                float* __restrict__ out) {
    out[0] = (float)(*counter) / (float)(NROWS * KSEL);
}

extern "C" void kernel_launch(void* const* d_in, const int* in_sizes, int n_in,
                              void* d_out, int out_size, void* d_ws, size_t ws_size,
                              hipStream_t stream) {
    (void)in_sizes; (void)n_in; (void)out_size; (void)ws_size;
    const int*   query_ids = (const int*)d_in[0];
    const int*   key_ids   = (const int*)d_in[1];
    const float* q         = (const float*)d_in[2];
    const float* kb        = (const float*)d_in[3];

    char* ws = (char*)d_ws;
    const size_t MB32 = (size_t)NROWS * DIM2 * sizeof(unsigned short);  // 32 MB
    int*            counter  = (int*)ws;
    unsigned short* Q2       = (unsigned short*)(ws + 256);
    unsigned short* K2       = (unsigned short*)(ws + 256 + MB32);
    float2*         partials = (float2*)(ws + 256 + 2 * MB32);

    hipMemsetAsync(counter, 0, sizeof(int), stream);
    prep_kernel<<<2 * NROWS, 128, 0, stream>>>(q, kb, Q2, K2);
    gemm_topk_kernel<<<dim3(NROWS / QB, NROWS / KBB), 256, 0, stream>>>(Q2, K2, partials);
    merge_kernel<<<NROWS / 32, 256, 0, stream>>>(partials, query_ids, key_ids, counter);
    finalize_kernel<<<1, 1, 0, stream>>>(counter, (float*)d_out);
}